// Round 5
// baseline (553.688 us; speedup 1.0000x reference)
//
#include <hip/hip_runtime.h>

// Unpool (conv_transpose2d, single-1 depthwise kernel), stride 2.
// in:  (8, 256, 112, 112) fp32;  out: (8, 256, 224, 224) fp32,
// out[:,:,::2,::2] = in, rest 0.
//
// v4 = DIAGNOSTIC build. v1's exact unit mapping (unit u = one float2 of
// input -> one float4 of even-row data + one float4 of odd-row zeros):
//   r = u/56, j = u%56
//   data:  out + 448r + 4j      = {x, 0, y, 0}
//   zeros: out + 448r + 224 + 4j
// Each thread executes TWO units: u1 = t, u2 = t +/- n/2 (half-domain
// offset). Both sweeps fully cover the output with identical values ->
// idempotent and correct (poisoned d_out is fully overwritten). The
// half-domain separation (~12 block-generations, ~100us) defeats L2
// absorption, so this dispatch does genuine 2x HBM traffic and runs
// ~2x the single-pass kernel time -> it exceeds the ~257us poison-fill
// cutoff and ITS OWN rocprof counter row becomes visible in top-5:
//   WRITE_SIZE  -> is there write amplification vs the 822MB ideal?
//   FETCH_SIZE  -> read inflation / L3 behavior
//   OccupancyPercent / VALUBusy -> occupancy- vs issue-limited
// Every output element written exactly once per pass.

__global__ __launch_bounds__(256) void unpool_x2dbg(
    const float2* __restrict__ in, float* __restrict__ out,
    unsigned n, unsigned half)
{
    const unsigned t = blockIdx.x * blockDim.x + threadIdx.x;
    if (t >= n) return;

    // Pass 1: unit t.
    {
        const unsigned u = t;
        const unsigned r = u / 56u, j = u - r * 56u;
        const float2 v = in[u];
        float* b = out + 448u * r + 4u * j;
        *reinterpret_cast<float4*>(b)       = make_float4(v.x, 0.f, v.y, 0.f);
        *reinterpret_cast<float4*>(b + 224) = make_float4(0.f, 0.f, 0.f, 0.f);
    }

    // Pass 2: unit t +/- n/2 (same values rewritten -> idempotent).
    {
        const unsigned u = (t >= half) ? (t - half) : (t + half);
        const unsigned r = u / 56u, j = u - r * 56u;
        const float2 v = in[u];
        float* b = out + 448u * r + 4u * j;
        *reinterpret_cast<float4*>(b)       = make_float4(v.x, 0.f, v.y, 0.f);
        *reinterpret_cast<float4*>(b + 224) = make_float4(0.f, 0.f, 0.f, 0.f);
    }
}

extern "C" void kernel_launch(void* const* d_in, const int* in_sizes, int n_in,
                              void* d_out, int out_size, void* d_ws, size_t ws_size,
                              hipStream_t stream)
{
    const float2* x = (const float2*)d_in[0];
    float* out      = (float*)d_out;

    // in_sizes[0] = 25,690,112 floats -> n = 12,845,056 float2 units.
    unsigned n    = (unsigned)in_sizes[0] / 2u;
    unsigned half = n / 2u;
    int block     = 256;
    int grid      = (int)((n + block - 1) / block);   // 50,176 blocks

    unpool_x2dbg<<<grid, block, 0, stream>>>(x, out, n, half);
}

// Round 6
// 457.910 us; speedup vs baseline: 1.2092x; 1.2092x over previous
//
#include <hip/hip_runtime.h>

// Unpool (conv_transpose2d, single-1 depthwise kernel), stride 2.
// in:  (8, 256, 112, 112) fp32;  out: (8, 256, 224, 224) fp32,
// out[:,:,::2,::2] = in, rest 0.
//
// v5 = v4 (the 2-pass diagnostic that sustained ~6.1 TB/s effective)
// with the redundant second coverage removed. Unit u = one float2 of
// input -> one float4 of even-row data + one float4 of odd-row zeros:
//   r = u/56, j = u%56
//   data:  out + 448r + 4j      = {x, 0, y, 0}
//   zeros: out + 448r + 224 + 4j
// Each thread t in [0, half) handles units t and t+half: two
// widely-separated sequential write frontiers, 2 loads + 4 stores per
// thread, every instruction wave-contiguous (512B loads, 1KB stores).
// Single exact coverage: every output element written exactly once
// (d_out is poisoned). 25,088 blocks of 256 threads.

__global__ __launch_bounds__(256) void unpool_dual(
    const float2* __restrict__ in, float* __restrict__ out, unsigned half)
{
    const unsigned t = blockIdx.x * blockDim.x + threadIdx.x;
    if (t >= half) return;

    const unsigned ua = t;
    const unsigned ub = t + half;

    // Two independent loads in flight per lane.
    const float2 va = in[ua];
    const float2 vb = in[ub];

    const unsigned ra = ua / 56u, ja = ua - ra * 56u;
    const unsigned rb = ub / 56u, jb = ub - rb * 56u;

    float* ba = out + 448u * ra + 4u * ja;
    float* bb = out + 448u * rb + 4u * jb;

    // Odd-row zeros first (independent of load results).
    *reinterpret_cast<float4*>(ba + 224) = make_float4(0.f, 0.f, 0.f, 0.f);
    *reinterpret_cast<float4*>(bb + 224) = make_float4(0.f, 0.f, 0.f, 0.f);

    // Even-row data.
    *reinterpret_cast<float4*>(ba) = make_float4(va.x, 0.f, va.y, 0.f);
    *reinterpret_cast<float4*>(bb) = make_float4(vb.x, 0.f, vb.y, 0.f);
}

extern "C" void kernel_launch(void* const* d_in, const int* in_sizes, int n_in,
                              void* d_out, int out_size, void* d_ws, size_t ws_size,
                              hipStream_t stream)
{
    const float2* x = (const float2*)d_in[0];
    float* out      = (float*)d_out;

    // in_sizes[0] = 25,690,112 floats -> n = 12,845,056 units, half = 6,422,528.
    unsigned n    = (unsigned)in_sizes[0] / 2u;
    unsigned half = n / 2u;
    int block     = 256;
    int grid      = (int)((half + block - 1) / block);   // 25,088 blocks

    unpool_dual<<<grid, block, 0, stream>>>(x, out, half);
}